// Round 2
// baseline (2231.754 us; speedup 1.0000x reference)
//
#include <hip/hip_runtime.h>
#include <hip/hip_bf16.h>

// Problem constants (MultiviewCrossAttnFeature)
#define NVOX 50000
#define MV   12
#define FD   256
#define AUGD 272   // FD + 16 extrinsics
#define BQ   16384
#define HN   8
#define DKC  64
#define HD   512   // HN*DKC
#define PEO  8

// ---------------- min/max over voxels (N,3), fp32 ----------------
__global__ void kmm_part(const float* __restrict__ vox, float* __restrict__ part) {
    int tid = threadIdx.x;
    float mn[3] = {1e30f, 1e30f, 1e30f};
    float mx[3] = {-1e30f, -1e30f, -1e30f};
    for (int i = blockIdx.x * 256 + tid; i < NVOX; i += 64 * 256) {
        #pragma unroll
        for (int c = 0; c < 3; ++c) {
            float v = vox[3 * i + c];
            mn[c] = fminf(mn[c], v);
            mx[c] = fmaxf(mx[c], v);
        }
    }
    #pragma unroll
    for (int s = 1; s < 64; s <<= 1) {
        #pragma unroll
        for (int c = 0; c < 3; ++c) {
            mn[c] = fminf(mn[c], __shfl_xor(mn[c], s, 64));
            mx[c] = fmaxf(mx[c], __shfl_xor(mx[c], s, 64));
        }
    }
    __shared__ float smn[4][3], smx[4][3];
    int w = tid >> 6;
    if ((tid & 63) == 0) {
        #pragma unroll
        for (int c = 0; c < 3; ++c) { smn[w][c] = mn[c]; smx[w][c] = mx[c]; }
    }
    __syncthreads();
    if (tid == 0) {
        #pragma unroll
        for (int c = 0; c < 3; ++c) {
            float a = fminf(fminf(smn[0][c], smn[1][c]), fminf(smn[2][c], smn[3][c]));
            float b = fmaxf(fmaxf(smx[0][c], smx[1][c]), fmaxf(smx[2][c], smx[3][c]));
            part[blockIdx.x * 6 + c] = a;
            part[blockIdx.x * 6 + 3 + c] = b;
        }
    }
}

__global__ void kmm_final(const float* __restrict__ part, float* __restrict__ mm) {
    int t = threadIdx.x;  // 64 threads = 1 wave
    float mn[3], mx[3];
    #pragma unroll
    for (int c = 0; c < 3; ++c) { mn[c] = part[t * 6 + c]; mx[c] = part[t * 6 + 3 + c]; }
    #pragma unroll
    for (int s = 1; s < 64; s <<= 1) {
        #pragma unroll
        for (int c = 0; c < 3; ++c) {
            mn[c] = fminf(mn[c], __shfl_xor(mn[c], s, 64));
            mx[c] = fmaxf(mx[c], __shfl_xor(mx[c], s, 64));
        }
    }
    if (t == 0) {
        #pragma unroll
        for (int c = 0; c < 3; ++c) { mm[c] = mn[c]; mm[3 + c] = mx[c]; }
    }
}

// ---------------- main fused kernel: 1 query voxel / block ----------------
// Thread j owns output columns (2j, 2j+1) -> head h = j/32.
// Wave w: lanes 0-31 -> head 2w, lanes 32-63 -> head 2w+1 (logit reduce within half-wave).
__global__ __launch_bounds__(256) void kattn(
    const int* __restrict__ vi, const float* __restrict__ voxels,
    const float* __restrict__ feats, const float* __restrict__ scores,
    const int* __restrict__ cams, const float* __restrict__ extr,
    const float* __restrict__ Wq, const float* __restrict__ Wk, const float* __restrict__ Wv,
    const float* __restrict__ mm, float* __restrict__ out)
{
    __shared__ float s_aug[MV * AUGD];   // [feats(256) | ext(16)] per view, fp32
    __shared__ float s_pe[24];
    __shared__ float s_mask[MV];

    const int b = blockIdx.x;
    const int tid = threadIdx.x;
    const int idx = vi[b];

    // ---- phase 1: stage gathered inputs ----
    const float4* f4 = (const float4*)(feats + (size_t)idx * (MV * FD));
    for (int i = tid; i < MV * FD / 4; i += 256) {   // 768 float4
        int m = i >> 6;            // 64 float4 per 256-elem view row
        int t = (i & 63) << 2;
        *(float4*)&s_aug[m * AUGD + t] = f4[i];
    }
    if (tid < MV * 16) {
        int m = tid >> 4, e = tid & 15;
        int cam = cams[idx * MV + m];
        s_aug[m * AUGD + FD + e] = extr[cam * 16 + e];
    }
    if (tid < MV) s_mask[tid] = (scores[idx * MV + tid] < 0.0f) ? -1e30f : 0.0f;
    if (tid < 24) {
        int p = tid / 3, c = tid % 3;
        float vmn = mm[c], vmx = mm[3 + c];
        float x = (voxels[idx * 3 + c] - vmn) / (vmx - vmn) - 0.5f;
        s_pe[tid] = sinf(x * (float)(1 << p));
    }
    __syncthreads();

    const int j = tid;
    const float2* Wq2 = (const float2*)Wq;  // row stride 256 float2 (512 floats)
    const float2* Wk2 = (const float2*)Wk;
    const float2* Wv2 = (const float2*)Wv;

    // ---- Q projection: columns 2j, 2j+1 ----
    float q0 = 0.f, q1 = 0.f;
    #pragma unroll
    for (int t = 0; t < 24; ++t) {
        float2 w = Wq2[t * 256 + j];
        float p = s_pe[t];
        q0 = fmaf(p, w.x, q0);
        q1 = fmaf(p, w.y, q1);
    }

    // ---- V projection (registers only) ----
    float v0[MV], v1[MV];
    #pragma unroll
    for (int m = 0; m < MV; ++m) { v0[m] = 0.f; v1[m] = 0.f; }
    for (int t = 0; t < FD; t += 4) {
        float2 w0 = Wv2[(t + 0) * 256 + j];
        float2 w1 = Wv2[(t + 1) * 256 + j];
        float2 w2 = Wv2[(t + 2) * 256 + j];
        float2 w3 = Wv2[(t + 3) * 256 + j];
        #pragma unroll
        for (int m = 0; m < MV; ++m) {
            float4 f = *(const float4*)&s_aug[m * AUGD + t];  // wave-broadcast
            v0[m] = fmaf(f.x, w0.x, v0[m]); v0[m] = fmaf(f.y, w1.x, v0[m]);
            v0[m] = fmaf(f.z, w2.x, v0[m]); v0[m] = fmaf(f.w, w3.x, v0[m]);
            v1[m] = fmaf(f.x, w0.y, v1[m]); v1[m] = fmaf(f.y, w1.y, v1[m]);
            v1[m] = fmaf(f.z, w2.y, v1[m]); v1[m] = fmaf(f.w, w3.y, v1[m]);
        }
    }

    // ---- K projection (registers only) ----
    float k0[MV], k1[MV];
    #pragma unroll
    for (int m = 0; m < MV; ++m) { k0[m] = 0.f; k1[m] = 0.f; }
    for (int t = 0; t < AUGD; t += 4) {
        float2 w0 = Wk2[(t + 0) * 256 + j];
        float2 w1 = Wk2[(t + 1) * 256 + j];
        float2 w2 = Wk2[(t + 2) * 256 + j];
        float2 w3 = Wk2[(t + 3) * 256 + j];
        #pragma unroll
        for (int m = 0; m < MV; ++m) {
            float4 f = *(const float4*)&s_aug[m * AUGD + t];
            k0[m] = fmaf(f.x, w0.x, k0[m]); k0[m] = fmaf(f.y, w1.x, k0[m]);
            k0[m] = fmaf(f.z, w2.x, k0[m]); k0[m] = fmaf(f.w, w3.x, k0[m]);
            k1[m] = fmaf(f.x, w0.y, k1[m]); k1[m] = fmaf(f.y, w1.y, k1[m]);
            k1[m] = fmaf(f.z, w2.y, k1[m]); k1[m] = fmaf(f.w, w3.y, k1[m]);
        }
    }

    // ---- logits: both columns of this thread belong to the same head ----
    float lp[MV];
    #pragma unroll
    for (int m = 0; m < MV; ++m) lp[m] = q0 * k0[m] + q1 * k1[m];
    #pragma unroll
    for (int s = 1; s < 32; s <<= 1) {
        #pragma unroll
        for (int m = 0; m < MV; ++m) lp[m] += __shfl_xor(lp[m], s, 64);
    }

    // ---- softmax over views (redundant per lane) ----
    float lg[MV], mxv = -1e30f;
    #pragma unroll
    for (int m = 0; m < MV; ++m) {
        lg[m] = lp[m] * 0.125f + s_mask[m];
        mxv = fmaxf(mxv, lg[m]);
    }
    float sum = 0.f, pr[MV];
    #pragma unroll
    for (int m = 0; m < MV; ++m) { pr[m] = __expf(lg[m] - mxv); sum += pr[m]; }
    float inv = 1.0f / sum;

    // ---- output: p . v, float2 store ----
    float o0 = 0.f, o1 = 0.f;
    #pragma unroll
    for (int m = 0; m < MV; ++m) { o0 = fmaf(pr[m], v0[m], o0); o1 = fmaf(pr[m], v1[m], o1); }
    o0 *= inv; o1 *= inv;
    ((float2*)out)[(size_t)b * (HD / 2) + j] = make_float2(o0, o1);
}

extern "C" void kernel_launch(void* const* d_in, const int* in_sizes, int n_in,
                              void* d_out, int out_size, void* d_ws, size_t ws_size,
                              hipStream_t stream) {
    const int*   vi      = (const int*)d_in[0];
    const float* voxels  = (const float*)d_in[1];
    const float* feats   = (const float*)d_in[2];
    const float* scores  = (const float*)d_in[3];
    const int*   cams    = (const int*)d_in[4];
    const float* extr    = (const float*)d_in[5];
    const float* Wq      = (const float*)d_in[6];
    const float* Wk      = (const float*)d_in[7];
    const float* Wv      = (const float*)d_in[8];
    float* out = (float*)d_out;

    float* ws   = (float*)d_ws;
    float* mm   = ws;        // 6 floats: vmin[3], vmax[3]
    float* part = ws + 8;    // 64 * 6 partials

    kmm_part<<<64, 256, 0, stream>>>(voxels, part);
    kmm_final<<<1, 64, 0, stream>>>(part, mm);
    kattn<<<BQ, 256, 0, stream>>>(vi, voxels, feats, scores, cams, extr, Wq, Wk, Wv, mm, out);
}